// Round 1
// baseline (21.808 us; speedup 1.0000x reference)
//
#include <hip/hip_runtime.h>

// WImage: per-pixel 21x21 gaussian-affinity sum over a zero-padded window,
// then affine rescale. image (1,3,256,256) f32, kernel=21 (fixed by setup).
//
// w(p) = sum_{n in 21x21 window} exp(-(n - c)^2 / (2*0.5^2)) - 1   (self term = 1)
// out  = ((c + 0.05*w) - mn) / (mx - mn) * 2 - 1
//   mn = -1 + 440*0.05*exp(-8), mx = 1 + 440*0.05 = 23

#define TS 16            // output tile side (16x16 threads, 1 px/thread)
#define KS 21            // kernel size (fixed by setup_inputs)
#define PAD 10           // KS/2
#define TILE (TS + 2*PAD)   // 36: input tile side incl. halo
#define LSTRIDE 48          // LDS row stride in floats; 48%32==16 -> rows map to
                            // bank offsets {0,16,0,16} across the wave's 4 rows
                            // = 2-way conflicts only (free on CDNA4)
#define H 256
#define W 256

__global__ __launch_bounds__(256)
void wimage_kernel(const float* __restrict__ img, float* __restrict__ out) {
    __shared__ float tile[TILE * LSTRIDE];

    const int tx = threadIdx.x;            // 0..15
    const int ty = threadIdx.y;            // 0..15
    const int tid = ty * TS + tx;
    const int bx = blockIdx.x * TS;
    const int by = blockIdx.y * TS;
    const int ch = blockIdx.z;

    const float* __restrict__ plane = img + ch * (H * W);

    // Cooperative load of the 36x36 halo tile with zero padding (Unfold semantics).
    for (int i = tid; i < TILE * TILE; i += TS * TS) {
        const int r   = i / TILE;
        const int col = i - r * TILE;
        const int gy  = by + r - PAD;
        const int gx  = bx + col - PAD;
        float v = 0.0f;
        if ((unsigned)gy < (unsigned)H && (unsigned)gx < (unsigned)W)
            v = plane[gy * W + gx];
        tile[r * LSTRIDE + col] = v;
    }
    __syncthreads();

    const float center = tile[(ty + PAD) * LSTRIDE + (tx + PAD)];

    float sum = 0.0f;
    for (int dy = 0; dy < KS; ++dy) {
        const float* row = &tile[(ty + dy) * LSTRIDE + tx];
        #pragma unroll
        for (int dx = 0; dx < KS; ++dx) {
            const float d = row[dx] - center;
            // exp(-(d^2)/(2*sigma^2)) with sigma=0.5 -> exp(-2*d^2)
            sum += __expf(d * d * -2.0f);
        }
    }

    // self term exp(0)=1 is included in sum; w = sum - 1
    const float alpha = 0.05f;
    // mn = -1 + 440*0.05*exp(-8) (double-precision derived)
    const float mn    = -0.99261982218614470f;
    const float scale = 2.0f / (23.0f - mn);   // 2/(mx-mn), mx=23

    const float v = center + alpha * (sum - 1.0f);
    out[ch * (H * W) + (by + ty) * W + (bx + tx)] = (v - mn) * scale - 1.0f;
}

extern "C" void kernel_launch(void* const* d_in, const int* in_sizes, int n_in,
                              void* d_out, int out_size, void* d_ws, size_t ws_size,
                              hipStream_t stream) {
    (void)in_sizes; (void)n_in; (void)d_ws; (void)ws_size;
    const float* img = (const float*)d_in[0];
    // d_in[1] is the kernel size (21) — fixed by setup_inputs, hardcoded above.
    float* out = (float*)d_out;
    (void)out_size;

    dim3 block(TS, TS, 1);
    dim3 grid(W / TS, H / TS, 3);
    wimage_kernel<<<grid, block, 0, stream>>>(img, out);
}

// Round 2
// 19.384 us; speedup vs baseline: 1.1251x; 1.1251x over previous
//
#include <hip/hip_runtime.h>

// WImage: per-pixel 21x21 gaussian-affinity sum over a zero-padded window, then
// affine rescale. image (1,3,256,256) f32, kernel=21 (fixed by setup_inputs).
//
// Factorization: exp(-2(n-c)^2) = exp2(Qc) * exp2(An + Bn*c)
//   An = -2*log2e*n^2,  Bn = 4*log2e*n,  Qc = -2*log2e*c^2 = A(center)
// => w(c) = exp2(Qc) * sum_n exp2(fma(Bn, c, An)) - 1   (self term included, =1)
// Per-pair cost: 1 v_fma + 1 v_exp + 1 v_add. (A,B) computed ONCE per halo
// pixel at staging time and stored interleaved in LDS (float2), read back as
// ds_read_b128 (2 neighbors per read, bank-conflict-free).

#define KS   21
#define PAD  10
#define TSX  32            // output tile width  (2 px per thread in x)
#define TSY  16            // output tile height
#define HALO_W (TSX + 2*PAD)   // 52
#define HALO_H (TSY + 2*PAD)   // 36
#define H 256
#define W 256

__global__ __launch_bounds__(256)
void wimage_kernel(const float* __restrict__ img, float* __restrict__ out) {
    __shared__ float2 ab[HALO_H * HALO_W];   // 36*52*8 = 14976 B

    const float LOG2E  = 1.4426950408889634f;
    const float KM2    = -2.0f * LOG2E;      // A = (v*KM2)*v
    const float K4     =  4.0f * LOG2E;      // B = v*K4
    const float INV_K4 = 0.17328679513998632f; // ln2/4: v = B*INV_K4

    const int tx  = threadIdx.x;             // 0..15
    const int ty  = threadIdx.y;             // 0..15
    const int tid = ty * 16 + tx;
    const int bx  = blockIdx.x * TSX;
    const int by  = blockIdx.y * TSY;
    const int ch  = blockIdx.z;
    const float* __restrict__ plane = img + ch * (H * W);

    // Stage halo tile, computing (A,B) per pixel once. Zero padding (Unfold
    // semantics): v=0 -> A=0,B=0 -> contributes exp2(Qc) = exp(-2c^2) correct.
    for (int i = tid; i < HALO_H * HALO_W; i += 256) {
        const int r   = i / HALO_W;
        const int col = i - r * HALO_W;
        const int gy  = by + r - PAD;
        const int gx  = bx + col - PAD;
        float v = 0.0f;
        if ((unsigned)gy < (unsigned)H && (unsigned)gx < (unsigned)W)
            v = plane[gy * W + gx];
        ab[i] = make_float2((v * KM2) * v, v * K4);
    }
    __syncthreads();

    // Two adjacent centers per thread: out cols (bx+2tx, bx+2tx+1), row by+ty.
    const float2 cab0 = ab[(ty + PAD) * HALO_W + 2 * tx + PAD];
    const float2 cab1 = ab[(ty + PAD) * HALO_W + 2 * tx + PAD + 1];
    const float Q0 = cab0.x, c0 = cab0.y * INV_K4;
    const float Q1 = cab1.x, c1 = cab1.y * INV_K4;

    float s0 = 0.0f, s1 = 0.0f;
    const float2* rp = &ab[ty * HALO_W + 2 * tx];  // row dy, halo col 2tx (16B aligned)
    for (int dy = 0; dy < KS; ++dy) {
        float A[22], B[22];
        #pragma unroll
        for (int i = 0; i < 11; ++i) {             // 22 neighbors via 11 b128 reads
            const float4 t = ((const float4*)rp)[i];
            A[2*i]   = t.x; B[2*i]   = t.y;
            A[2*i+1] = t.z; B[2*i+1] = t.w;
        }
        #pragma unroll
        for (int i = 0; i < KS; ++i) {
            s0 += __builtin_amdgcn_exp2f(fmaf(B[i],     c0, A[i]));
            s1 += __builtin_amdgcn_exp2f(fmaf(B[i + 1], c1, A[i + 1]));
        }
        rp += HALO_W;
    }

    const float alpha = 0.05f;
    const float mn    = -0.99261982218614470f;   // -1 + 22*exp(-8)
    const float scale = 2.0f / (23.0f - mn);     // 2/(mx-mn), mx = 1 + 440*0.05

    const float w0 = __builtin_amdgcn_exp2f(Q0) * s0 - 1.0f;
    const float w1 = __builtin_amdgcn_exp2f(Q1) * s1 - 1.0f;
    const float o0 = (c0 + alpha * w0 - mn) * scale - 1.0f;
    const float o1 = (c1 + alpha * w1 - mn) * scale - 1.0f;

    *(float2*)&out[ch * (H * W) + (by + ty) * W + bx + 2 * tx] = make_float2(o0, o1);
}

extern "C" void kernel_launch(void* const* d_in, const int* in_sizes, int n_in,
                              void* d_out, int out_size, void* d_ws, size_t ws_size,
                              hipStream_t stream) {
    (void)in_sizes; (void)n_in; (void)d_ws; (void)ws_size; (void)out_size;
    const float* img = (const float*)d_in[0];   // d_in[1] = kernel size (21), hardcoded
    float* out = (float*)d_out;

    dim3 block(16, 16, 1);
    dim3 grid(W / TSX, H / TSY, 3);             // 8 x 16 x 3 = 384 blocks
    wimage_kernel<<<grid, block, 0, stream>>>(img, out);
}